// Round 1
// baseline (398.876 us; speedup 1.0000x reference)
//
#include <hip/hip_runtime.h>

#define BB 4
#define NN 100000
#define KK 16
#define DD 6
#define FF 13
#define LL 3
#define NPTS (BB * NN)
#define EPS 1e-5f
#define SLOPE 0.2f

__global__ __launch_bounds__(256) void atom_mp_kernel(
    const float* __restrict__ dist,      // [B,N,K,1]
    const float* __restrict__ atomtypes, // [B,N,K,D]
    const float* __restrict__ w1,        // [L,F,F]
    const float* __restrict__ b1,        // [L,F]
    const float* __restrict__ w2,        // [L,F,D]
    const float* __restrict__ b2,        // [L,D]
    const float* __restrict__ gnw,       // [L,D]
    const float* __restrict__ gnb,       // [L,D]
    float* __restrict__ out)             // [B,N,D]
{
    __shared__ float s_w1[LL * FF * FF];   // 507
    __shared__ float s_b1[LL * FF];        // 39
    __shared__ float s_w2[LL * FF * DD];   // 234
    __shared__ float s_b2[LL * DD];        // 18
    __shared__ float s_gnw[LL * DD];
    __shared__ float s_gnb[LL * DD];

    for (int i = threadIdx.x; i < LL * FF * FF; i += blockDim.x) s_w1[i] = w1[i];
    for (int i = threadIdx.x; i < LL * FF;      i += blockDim.x) s_b1[i] = b1[i];
    for (int i = threadIdx.x; i < LL * FF * DD; i += blockDim.x) s_w2[i] = w2[i];
    for (int i = threadIdx.x; i < LL * DD;      i += blockDim.x) {
        s_b2[i]  = b2[i];
        s_gnw[i] = gnw[i];
        s_gnb[i] = gnb[i];
    }
    __syncthreads();

    const int p = blockIdx.x * blockDim.x + threadIdx.x;
    if (p >= NPTS) return;

    const float* __restrict__ atp = atomtypes + (size_t)p * (KK * DD);
    const float* __restrict__ dp  = dist + (size_t)p * KK;

    float pe[DD];
    #pragma unroll
    for (int d = 0; d < DD; ++d) pe[d] = 1.0f;

    for (int l = 0; l < LL; ++l) {
        const float* __restrict__ lw1 = s_w1 + l * FF * FF;
        const float* __restrict__ lb1 = s_b1 + l * FF;
        const float* __restrict__ lw2 = s_w2 + l * FF * DD;
        const float* __restrict__ lb2 = s_b2 + l * DD;

        // base[j] = b1[j] + sum_d pe[d] * w1[d][j]   (k-invariant part of feat@W1)
        float base[FF];
        #pragma unroll
        for (int j = 0; j < FF; ++j) base[j] = lb1[j];
        #pragma unroll
        for (int d = 0; d < DD; ++d) {
            const float x = pe[d];
            #pragma unroll
            for (int j = 0; j < FF; ++j) base[j] = fmaf(x, lw1[d * FF + j], base[j]);
        }

        float msg[DD];
        #pragma unroll
        for (int d = 0; d < DD; ++d) msg[d] = (float)KK * lb2[d];

        for (int k = 0; k < KK; ++k) {
            // load neighbor features (6 floats, 8B-aligned) + dist
            const float2 a01 = *reinterpret_cast<const float2*>(atp + k * DD + 0);
            const float2 a23 = *reinterpret_cast<const float2*>(atp + k * DD + 2);
            const float2 a45 = *reinterpret_cast<const float2*>(atp + k * DD + 4);
            const float dk = dp[k];
            float at[DD];
            at[0] = a01.x; at[1] = a01.y;
            at[2] = a23.x; at[3] = a23.y;
            at[4] = a45.x; at[5] = a45.y;

            float h[FF];
            #pragma unroll
            for (int j = 0; j < FF; ++j) h[j] = base[j];
            #pragma unroll
            for (int d = 0; d < DD; ++d) {
                const float x = at[d];
                #pragma unroll
                for (int j = 0; j < FF; ++j) h[j] = fmaf(x, lw1[(DD + d) * FF + j], h[j]);
            }
            #pragma unroll
            for (int j = 0; j < FF; ++j) h[j] = fmaf(dk, lw1[(2 * DD) * FF + j], h[j]);

            #pragma unroll
            for (int j = 0; j < FF; ++j) h[j] = h[j] > 0.0f ? h[j] : SLOPE * h[j];

            #pragma unroll
            for (int j = 0; j < FF; ++j) {
                const float x = h[j];
                #pragma unroll
                for (int d = 0; d < DD; ++d) msg[d] = fmaf(x, lw2[j * DD + d], msg[d]);
            }
        }

        // GroupNorm: 2 groups of 3 channels, biased variance
        float o[DD];
        #pragma unroll
        for (int g = 0; g < 2; ++g) {
            const float m0 = msg[g * 3 + 0];
            const float m1 = msg[g * 3 + 1];
            const float m2 = msg[g * 3 + 2];
            const float mu = (m0 + m1 + m2) * (1.0f / 3.0f);
            const float d0 = m0 - mu, d1 = m1 - mu, d2 = m2 - mu;
            const float var = (d0 * d0 + d1 * d1 + d2 * d2) * (1.0f / 3.0f);
            const float rs = rsqrtf(var + EPS);
            o[g * 3 + 0] = d0 * rs;
            o[g * 3 + 1] = d1 * rs;
            o[g * 3 + 2] = d2 * rs;
        }
        #pragma unroll
        for (int d = 0; d < DD; ++d) {
            float x = fmaf(o[d], s_gnw[l * DD + d], s_gnb[l * DD + d]);
            x = x > 0.0f ? x : SLOPE * x;
            pe[d] += x;
        }
    }

    float* __restrict__ op = out + (size_t)p * DD;
    #pragma unroll
    for (int d = 0; d < DD; ++d) op[d] = pe[d];
}

extern "C" void kernel_launch(void* const* d_in, const int* in_sizes, int n_in,
                              void* d_out, int out_size, void* d_ws, size_t ws_size,
                              hipStream_t stream) {
    const float* dist      = (const float*)d_in[0];
    const float* atomtypes = (const float*)d_in[1];
    const float* w1        = (const float*)d_in[2];
    const float* b1        = (const float*)d_in[3];
    const float* w2        = (const float*)d_in[4];
    const float* b2        = (const float*)d_in[5];
    const float* gnw       = (const float*)d_in[6];
    const float* gnb       = (const float*)d_in[7];
    float* out             = (float*)d_out;

    const int threads = 256;
    const int blocks = (NPTS + threads - 1) / threads;
    atom_mp_kernel<<<blocks, threads, 0, stream>>>(dist, atomtypes, w1, b1, w2, b2,
                                                   gnw, gnb, out);
}